// Round 4
// baseline (269.505 us; speedup 1.0000x reference)
//
#include <hip/hip_runtime.h>
#include <math.h>

#define N_NODES  50000
#define N_EDGES  800000
#define IN_DIM   64
#define HID_DIM  64
#define N_CLS    10
#define NBLK     ((N_NODES + 255) / 256)   // 196 scan blocks

// ---------------- zero degree counters ----------------
__global__ void k_zero(int* __restrict__ cnt) {
    int i = blockIdx.x * blockDim.x + threadIdx.x;
    if (i < N_NODES) cnt[i] = 0;
}

// ---------------- histogram of dst ----------------
__global__ void k_hist(const int* __restrict__ dst, int* __restrict__ cnt) {
    int e = blockIdx.x * blockDim.x + threadIdx.x;
    if (e < N_EDGES) atomicAdd(&cnt[dst[e]], 1);
}

// ---------------- scan phase A: per-block sums ----------------
__global__ __launch_bounds__(256) void k_blocksum(const int* __restrict__ cnt,
                                                  int* __restrict__ partial) {
    __shared__ int sw[4];
    int t = threadIdx.x;
    int i = blockIdx.x * 256 + t;
    int c = (i < N_NODES) ? cnt[i] : 0;
#pragma unroll
    for (int k = 1; k < 64; k <<= 1) c += __shfl_xor(c, k, 64);
    if ((t & 63) == 0) sw[t >> 6] = c;
    __syncthreads();
    if (t == 0) partial[blockIdx.x] = sw[0] + sw[1] + sw[2] + sw[3];
}

// ---------------- scan phase B: scan the partials (tiny) ----------------
__global__ __launch_bounds__(256) void k_scanpart(int* __restrict__ partial,
                                                  int* __restrict__ off) {
    __shared__ int s[256];
    int t = threadIdx.x;
    int v = (t < NBLK) ? partial[t] : 0;
    s[t] = v;
    __syncthreads();
    for (int d = 1; d < 256; d <<= 1) {
        int u = 0;
        if (t >= d) u = s[t - d];
        __syncthreads();
        if (t >= d) s[t] += u;
        __syncthreads();
    }
    if (t < NBLK) partial[t] = s[t] - v;   // exclusive
    if (t == 0) off[N_NODES] = N_EDGES;
}

// ---------------- scan phase C: in-block scan; write off, cursor(=off), dinv ----------------
__global__ __launch_bounds__(256) void k_blockscan(const int* __restrict__ cnt,
                                                   const int* __restrict__ partial,
                                                   int* __restrict__ off,
                                                   int* __restrict__ cursor,
                                                   float* __restrict__ dinv) {
    __shared__ int s[256];
    int t = threadIdx.x;
    int i = blockIdx.x * 256 + t;
    int c = (i < N_NODES) ? cnt[i] : 0;
    s[t] = c;
    __syncthreads();
    for (int d = 1; d < 256; d <<= 1) {
        int u = 0;
        if (t >= d) u = s[t - d];
        __syncthreads();
        if (t >= d) s[t] += u;
        __syncthreads();
    }
    if (i < N_NODES) {
        int o = partial[blockIdx.x] + s[t] - c;        // exclusive prefix
        off[i] = o;
        cursor[i] = o;                                 // scatter cursor starts at off
        dinv[i] = rsqrtf((float)(c + 1));              // +1 self-loop
    }
}

// ---------------- scatter edges into CSR (src index only) ----------------
__global__ void k_scatter(const int* __restrict__ src, const int* __restrict__ dst,
                          int* __restrict__ cursor, int* __restrict__ csr_src) {
    int e = blockIdx.x * blockDim.x + threadIdx.x;
    if (e >= N_EDGES) return;
    int s = src[e], t = dst[e];
    int slot = atomicAdd(&cursor[t], 1);
    csr_src[slot] = s;
}

// ---------------- xl' = (x @ W1) * dinv[row]  (N x 64)(64 x 64), W1 in LDS ----------------
__global__ __launch_bounds__(256) void k_xw64(const float* __restrict__ x,
                                              const float* __restrict__ W,
                                              const float* __restrict__ dinv,
                                              float* __restrict__ out) {
    __shared__ float sW[IN_DIM * HID_DIM];
    int tid = threadIdx.x;
    for (int i = tid; i < IN_DIM * HID_DIM; i += 256) sW[i] = W[i];
    __syncthreads();
    int col = tid & 63;
    int row = blockIdx.x * 4 + (tid >> 6);
    if (row >= N_NODES) return;
    const float* xr = x + (size_t)row * IN_DIM;
    float acc = 0.0f;
#pragma unroll
    for (int k = 0; k < IN_DIM; ++k) acc += xr[k] * sW[k * HID_DIM + col];
    out[(size_t)row * HID_DIM + col] = acc * dinv[row];
}

// ---------------- layer-1 gather: h = relu(dinv[t]*(xl'[t]+sum xl'[s]) + b1) ----------------
__global__ __launch_bounds__(256) void k_gather64(const float* __restrict__ xlp,
                                                  const int* __restrict__ csr_src,
                                                  const int* __restrict__ off,
                                                  const float* __restrict__ dinv,
                                                  const float* __restrict__ b1,
                                                  float* __restrict__ h) {
    int node = blockIdx.x * 4 + (threadIdx.x >> 6);
    int d = threadIdx.x & 63;
    if (node >= N_NODES) return;
    int beg = off[node], end = off[node + 1];
    float acc = xlp[(size_t)node * 64 + d];           // self-loop (dinv folded in)
    int j = beg;
    for (; j + 4 <= end; j += 4) {                    // 4 independent gathers in flight
        int s0 = csr_src[j],     s1 = csr_src[j + 1];
        int s2 = csr_src[j + 2], s3 = csr_src[j + 3];
        float v0 = xlp[(size_t)s0 * 64 + d];
        float v1 = xlp[(size_t)s1 * 64 + d];
        float v2 = xlp[(size_t)s2 * 64 + d];
        float v3 = xlp[(size_t)s3 * 64 + d];
        acc += (v0 + v1) + (v2 + v3);
    }
    for (; j < end; ++j)
        acc += xlp[(size_t)csr_src[j] * 64 + d];
    h[(size_t)node * 64 + d] = fmaxf(dinv[node] * acc + b1[d], 0.0f);
}

// ---------------- hl' = (h @ W2) * dinv[row]  (N x 64)(64 x 10), W2 in LDS ----------------
__global__ __launch_bounds__(256) void k_xw10(const float* __restrict__ h,
                                              const float* __restrict__ W,
                                              const float* __restrict__ dinv,
                                              float* __restrict__ out) {
    __shared__ float sW[HID_DIM * N_CLS];
    int tid = threadIdx.x;
    for (int i = tid; i < HID_DIM * N_CLS; i += 256) sW[i] = W[i];
    __syncthreads();
    int idx = blockIdx.x * 256 + tid;
    if (idx >= N_NODES * N_CLS) return;
    int row = idx / N_CLS;
    int col = idx - row * N_CLS;
    const float* hr = h + (size_t)row * HID_DIM;
    float acc = 0.0f;
#pragma unroll
    for (int k = 0; k < HID_DIM; ++k) acc += hr[k] * sW[k * N_CLS + col];
    out[idx] = acc * dinv[row];
}

// ---------------- layer-2 gather + b2 + log_softmax, 16-lane group per node ----------------
__global__ __launch_bounds__(256) void k_gather10(const float* __restrict__ hlp,
                                                  const int* __restrict__ csr_src,
                                                  const int* __restrict__ off,
                                                  const float* __restrict__ dinv,
                                                  const float* __restrict__ b2,
                                                  float* __restrict__ out) {
    int t = threadIdx.x;
    int node = blockIdx.x * 16 + (t >> 4);
    int d = t & 15;
    if (node >= N_NODES) return;
    bool act = d < N_CLS;
    int beg = off[node], end = off[node + 1];
    float acc = act ? hlp[(size_t)node * N_CLS + d] : 0.0f;
    for (int j = beg; j < end; ++j) {
        int s = csr_src[j];
        if (act) acc += hlp[(size_t)s * N_CLS + d];
    }
    float v = act ? dinv[node] * acc + b2[d] : -INFINITY;
    float m = v;
#pragma unroll
    for (int k = 1; k < 16; k <<= 1) m = fmaxf(m, __shfl_xor(m, k, 64));
    float ex = act ? expf(v - m) : 0.0f;
    float ssum = ex;
#pragma unroll
    for (int k = 1; k < 16; k <<= 1) ssum += __shfl_xor(ssum, k, 64);
    if (act) out[(size_t)node * N_CLS + d] = v - m - logf(ssum);
}

extern "C" void kernel_launch(void* const* d_in, const int* in_sizes, int n_in,
                              void* d_out, int out_size, void* d_ws, size_t ws_size,
                              hipStream_t stream) {
    const float* x  = (const float*)d_in[0];
    const int*   ei = (const int*)d_in[1];
    const float* W1 = (const float*)d_in[2];
    const float* b1 = (const float*)d_in[3];
    const float* W2 = (const float*)d_in[4];
    const float* b2 = (const float*)d_in[5];
    float* out = (float*)d_out;

    const int* src = ei;             // edge_index[0]
    const int* dst = ei + N_EDGES;   // edge_index[1]

    // workspace layout
    int*   cnt     = (int*)d_ws;                  // 50048
    int*   cursor  = cnt + 50048;                 // 50048
    int*   off     = cursor + 50048;              // 50056 (N+1 used)
    int*   partial = off + 50056;                 // 256
    int*   csr_src = partial + 256;               // 800000
    float* dinv    = (float*)(csr_src + N_EDGES); // 50048
    float* xl      = dinv + 50048;                // 3,200,000
    float* h       = xl + (size_t)N_NODES * 64;   // 3,200,000
    float* hl      = xl;                          // aliases dead xl

    const int B = 256;
    int g_nodes = (N_NODES + B - 1) / B;          // 196
    int g_edges = (N_EDGES + B - 1) / B;          // 3125
    int g_rows4 = (N_NODES + 3) / 4;              // 12500
    int g_n10   = (N_NODES * N_CLS + B - 1) / B;  // 1954
    int g_g10   = (N_NODES + 15) / 16;            // 3125

    k_zero     <<<g_nodes, B, 0, stream>>>(cnt);
    k_hist     <<<g_edges, B, 0, stream>>>(dst, cnt);
    k_blocksum <<<NBLK,    B, 0, stream>>>(cnt, partial);
    k_scanpart <<<1,       B, 0, stream>>>(partial, off);
    k_blockscan<<<NBLK,    B, 0, stream>>>(cnt, partial, off, cursor, dinv);
    k_xw64     <<<g_rows4, B, 0, stream>>>(x, W1, dinv, xl);
    k_scatter  <<<g_edges, B, 0, stream>>>(src, dst, cursor, csr_src);
    k_gather64 <<<g_rows4, B, 0, stream>>>(xl, csr_src, off, dinv, b1, h);
    k_xw10     <<<g_n10,   B, 0, stream>>>(h, W2, dinv, hl);
    k_gather10 <<<g_g10,   B, 0, stream>>>(hl, csr_src, off, dinv, b2, out);
}

// Round 5
// 207.610 us; speedup vs baseline: 1.2981x; 1.2981x over previous
//
#include <hip/hip_runtime.h>
#include <math.h>

#define N_NODES  50000
#define N_EDGES  800000
#define IN_DIM   64
#define HID_DIM  64
#define N_CLS    10
#define NBUCK    196      // ceil(N_NODES/256) coarse buckets (dst >> 8)
#define PBLK     64       // partition blocks
#define PCHUNK   (N_EDGES / PBLK)   // 12500 edges per partition block (exact)
#define SCANTOT  (NBUCK * PBLK)     // 12544

// ---------------- pass 1a: per-block coarse histogram (dst>>8) ----------------
__global__ __launch_bounds__(1024) void k_chist(const int* __restrict__ dst,
                                                int* __restrict__ bhist) {
    __shared__ int lh[NBUCK];
    int t = threadIdx.x;
    for (int i = t; i < NBUCK; i += 1024) lh[i] = 0;
    __syncthreads();
    int beg = blockIdx.x * PCHUNK, end = beg + PCHUNK;
    for (int e = beg + t; e < end; e += 1024)
        atomicAdd(&lh[dst[e] >> 8], 1);          // LDS atomic
    __syncthreads();
    for (int i = t; i < NBUCK; i += 1024)
        bhist[i * PBLK + blockIdx.x] = lh[i];    // bin-major
}

// ---------------- pass 1b: scan 12544 (bin,block) counts in LDS ----------------
__global__ __launch_bounds__(1024) void k_cscan(int* __restrict__ bhist,
                                                int* __restrict__ bbase,
                                                int* __restrict__ off) {
    __shared__ int s[SCANTOT];
    __shared__ int tsum[1024];
    int t = threadIdx.x;
    for (int i = t; i < SCANTOT; i += 1024) s[i] = bhist[i];   // coalesced
    __syncthreads();
    const int IT = (SCANTOT + 1023) / 1024;  // 13
    int base_i = t * IT;
    int sum = 0;
    for (int j = 0; j < IT; ++j) {
        int i = base_i + j;
        if (i < SCANTOT) sum += s[i];
    }
    tsum[t] = sum;
    __syncthreads();
    for (int d = 1; d < 1024; d <<= 1) {
        int v = (t >= d) ? tsum[t - d] : 0;
        __syncthreads();
        if (t >= d) tsum[t] += v;
        __syncthreads();
    }
    int run = (t > 0) ? tsum[t - 1] : 0;
    for (int j = 0; j < IT; ++j) {
        int i = base_i + j;
        if (i < SCANTOT) { int c = s[i]; s[i] = run; run += c; }
    }
    __syncthreads();
    for (int i = t; i < SCANTOT; i += 1024) bhist[i] = s[i];
    for (int i = t; i < NBUCK; i += 1024) bbase[i] = s[i * PBLK];
    if (t == 0) { bbase[NBUCK] = N_EDGES; off[N_NODES] = N_EDGES; }
}

// ---------------- pass 1c: partition edges into coarse buckets (packed) ----------------
__global__ __launch_bounds__(1024) void k_partition(const int* __restrict__ src,
                                                    const int* __restrict__ dst,
                                                    const int* __restrict__ bhist,
                                                    int* __restrict__ packed) {
    __shared__ int cur[NBUCK];
    int t = threadIdx.x;
    for (int i = t; i < NBUCK; i += 1024)
        cur[i] = bhist[i * PBLK + blockIdx.x];
    __syncthreads();
    int beg = blockIdx.x * PCHUNK, end = beg + PCHUNK;
    for (int e = beg + t; e < end; e += 1024) {
        int d = dst[e], sv = src[e];
        int slot = atomicAdd(&cur[d >> 8], 1);          // LDS atomic
        packed[slot] = ((d & 255) << 16) | sv;          // run-contiguous per (blk,bin)
    }
}

// ---------------- pass 2: per-bucket fine CSR + off + dinv ----------------
__global__ __launch_bounds__(1024) void k_fine(const int* __restrict__ packed,
                                               const int* __restrict__ bbase,
                                               int* __restrict__ off,
                                               float* __restrict__ dinv,
                                               int* __restrict__ csr_src) {
    __shared__ int hist[256];
    __shared__ int scan[256];
    __shared__ int cur[256];
    int t = threadIdx.x;
    int bucket = blockIdx.x;
    if (t < 256) hist[t] = 0;
    __syncthreads();
    int beg = bbase[bucket], end = bbase[bucket + 1];
    for (int i = beg + t; i < end; i += 1024)
        atomicAdd(&hist[packed[i] >> 16], 1);
    __syncthreads();
    if (t < 256) scan[t] = hist[t];
    __syncthreads();
    for (int d = 1; d < 256; d <<= 1) {
        int v = 0;
        if (t < 256 && t >= d) v = scan[t - d];
        __syncthreads();
        if (t < 256 && t >= d) scan[t] += v;
        __syncthreads();
    }
    if (t < 256) {
        int excl = beg + scan[t] - hist[t];
        cur[t] = excl;
        int node = bucket * 256 + t;
        if (node < N_NODES) {
            off[node] = excl;
            dinv[node] = rsqrtf((float)(hist[t] + 1));   // +1 self-loop
        }
    }
    __syncthreads();
    for (int i = beg + t; i < end; i += 1024) {
        int p = packed[i];
        int slot = atomicAdd(&cur[p >> 16], 1);          // LDS atomic
        csr_src[slot] = p & 0xFFFF;                      // within one ~16KB window
    }
}

// ---------------- xl' = (x @ W1) * dinv[row], W1 in LDS ----------------
__global__ __launch_bounds__(256) void k_xw64(const float* __restrict__ x,
                                              const float* __restrict__ W,
                                              const float* __restrict__ dinv,
                                              float* __restrict__ out) {
    __shared__ float sW[IN_DIM * HID_DIM];
    int tid = threadIdx.x;
    for (int i = tid; i < IN_DIM * HID_DIM; i += 256) sW[i] = W[i];
    __syncthreads();
    int col = tid & 63;
    int row = blockIdx.x * 4 + (tid >> 6);
    if (row >= N_NODES) return;
    const float* xr = x + (size_t)row * IN_DIM;
    float acc = 0.0f;
#pragma unroll
    for (int k = 0; k < IN_DIM; ++k) acc += xr[k] * sW[k * HID_DIM + col];
    out[(size_t)row * HID_DIM + col] = acc * dinv[row];
}

// ---------------- layer-1 gather: h = relu(dinv[t]*(xl'[t]+sum xl'[s]) + b1) ----------------
__global__ __launch_bounds__(256) void k_gather64(const float* __restrict__ xlp,
                                                  const int* __restrict__ csr_src,
                                                  const int* __restrict__ off,
                                                  const float* __restrict__ dinv,
                                                  const float* __restrict__ b1,
                                                  float* __restrict__ h) {
    int node = blockIdx.x * 4 + (threadIdx.x >> 6);
    int d = threadIdx.x & 63;
    if (node >= N_NODES) return;
    int beg = off[node], end = off[node + 1];
    float acc = xlp[(size_t)node * 64 + d];           // self-loop (dinv folded in)
    int j = beg;
    for (; j + 4 <= end; j += 4) {                    // 4 independent gathers in flight
        int s0 = csr_src[j],     s1 = csr_src[j + 1];
        int s2 = csr_src[j + 2], s3 = csr_src[j + 3];
        float v0 = xlp[(size_t)s0 * 64 + d];
        float v1 = xlp[(size_t)s1 * 64 + d];
        float v2 = xlp[(size_t)s2 * 64 + d];
        float v3 = xlp[(size_t)s3 * 64 + d];
        acc += (v0 + v1) + (v2 + v3);
    }
    for (; j < end; ++j)
        acc += xlp[(size_t)csr_src[j] * 64 + d];
    h[(size_t)node * 64 + d] = fmaxf(dinv[node] * acc + b1[d], 0.0f);
}

// ---------------- hl' = (h @ W2) * dinv[row], W2 in LDS ----------------
__global__ __launch_bounds__(256) void k_xw10(const float* __restrict__ h,
                                              const float* __restrict__ W,
                                              const float* __restrict__ dinv,
                                              float* __restrict__ out) {
    __shared__ float sW[HID_DIM * N_CLS];
    int tid = threadIdx.x;
    for (int i = tid; i < HID_DIM * N_CLS; i += 256) sW[i] = W[i];
    __syncthreads();
    int idx = blockIdx.x * 256 + tid;
    if (idx >= N_NODES * N_CLS) return;
    int row = idx / N_CLS;
    int col = idx - row * N_CLS;
    const float* hr = h + (size_t)row * HID_DIM;
    float acc = 0.0f;
#pragma unroll
    for (int k = 0; k < HID_DIM; ++k) acc += hr[k] * sW[k * N_CLS + col];
    out[idx] = acc * dinv[row];
}

// ---------------- layer-2 gather + b2 + log_softmax, 16-lane group per node ----------------
__global__ __launch_bounds__(256) void k_gather10(const float* __restrict__ hlp,
                                                  const int* __restrict__ csr_src,
                                                  const int* __restrict__ off,
                                                  const float* __restrict__ dinv,
                                                  const float* __restrict__ b2,
                                                  float* __restrict__ out) {
    int t = threadIdx.x;
    int node = blockIdx.x * 16 + (t >> 4);
    int d = t & 15;
    if (node >= N_NODES) return;
    bool act = d < N_CLS;
    int beg = off[node], end = off[node + 1];
    float acc = act ? hlp[(size_t)node * N_CLS + d] : 0.0f;
    for (int j = beg; j < end; ++j) {
        int s = csr_src[j];
        if (act) acc += hlp[(size_t)s * N_CLS + d];
    }
    float v = act ? dinv[node] * acc + b2[d] : -INFINITY;
    float m = v;
#pragma unroll
    for (int k = 1; k < 16; k <<= 1) m = fmaxf(m, __shfl_xor(m, k, 64));
    float ex = act ? expf(v - m) : 0.0f;
    float ssum = ex;
#pragma unroll
    for (int k = 1; k < 16; k <<= 1) ssum += __shfl_xor(ssum, k, 64);
    if (act) out[(size_t)node * N_CLS + d] = v - m - logf(ssum);
}

extern "C" void kernel_launch(void* const* d_in, const int* in_sizes, int n_in,
                              void* d_out, int out_size, void* d_ws, size_t ws_size,
                              hipStream_t stream) {
    const float* x  = (const float*)d_in[0];
    const int*   ei = (const int*)d_in[1];
    const float* W1 = (const float*)d_in[2];
    const float* b1 = (const float*)d_in[3];
    const float* W2 = (const float*)d_in[4];
    const float* b2 = (const float*)d_in[5];
    float* out = (float*)d_out;

    const int* src = ei;             // edge_index[0]
    const int* dst = ei + N_EDGES;   // edge_index[1]

    // workspace layout
    int*   bhist   = (int*)d_ws;                  // 12544 (pad 12800)
    int*   bbase   = bhist + 12800;               // 197  (pad 256)
    int*   off     = bbase + 256;                 // 50001 (pad 50432)
    int*   packed  = off + 50432;                 // 800000
    int*   csr_src = packed + N_EDGES;            // 800000
    float* dinv    = (float*)(csr_src + N_EDGES); // 50000 (pad 50048)
    float* xl      = dinv + 50048;                // 3,200,000
    float* h       = xl + (size_t)N_NODES * 64;   // 3,200,000
    float* hl      = xl;                          // aliases dead xl

    const int B = 256;
    int g_rows4 = (N_NODES + 3) / 4;              // 12500
    int g_n10   = (N_NODES * N_CLS + B - 1) / B;  // 1954
    int g_g10   = (N_NODES + 15) / 16;            // 3125
    int g_nodes = (N_NODES + B - 1) / B;          // 196

    k_chist    <<<PBLK,  1024, 0, stream>>>(dst, bhist);
    k_cscan    <<<1,     1024, 0, stream>>>(bhist, bbase, off);
    k_partition<<<PBLK,  1024, 0, stream>>>(src, dst, bhist, packed);
    k_fine     <<<NBUCK, 1024, 0, stream>>>(packed, bbase, off, dinv, csr_src);
    k_xw64     <<<g_rows4, B, 0, stream>>>(x, W1, dinv, xl);
    k_gather64 <<<g_rows4, B, 0, stream>>>(xl, csr_src, off, dinv, b1, h);
    k_xw10     <<<g_n10,   B, 0, stream>>>(h, W2, dinv, hl);
    k_gather10 <<<g_g10,   B, 0, stream>>>(hl, csr_src, off, dinv, b2, out);
    (void)g_nodes; (void)in_sizes; (void)n_in; (void)out_size; (void)ws_size;
}

// Round 6
// 189.105 us; speedup vs baseline: 1.4252x; 1.0979x over previous
//
#include <hip/hip_runtime.h>
#include <math.h>

#define N_NODES  50000
#define N_EDGES  800000
#define IN_DIM   64
#define HID_DIM  64
#define N_CLS    10
#define NBUCK    196      // ceil(N_NODES/256) coarse buckets (dst >> 8)
#define PBLK     64       // partition blocks
#define PCHUNK   (N_EDGES / PBLK)   // 12500 edges per partition block (exact)
#define SCANTOT  (NBUCK * PBLK)     // 12544

// ---------------- pass 1a: per-block coarse histogram (dst>>8) ----------------
__global__ __launch_bounds__(1024) void k_chist(const int* __restrict__ dst,
                                                int* __restrict__ bhist) {
    __shared__ int lh[NBUCK];
    int t = threadIdx.x;
    for (int i = t; i < NBUCK; i += 1024) lh[i] = 0;
    __syncthreads();
    int beg = blockIdx.x * PCHUNK, end = beg + PCHUNK;
    for (int e = beg + t; e < end; e += 1024)
        atomicAdd(&lh[dst[e] >> 8], 1);          // LDS atomic
    __syncthreads();
    for (int i = t; i < NBUCK; i += 1024)
        bhist[i * PBLK + blockIdx.x] = lh[i];    // bin-major
}

// ---------------- pass 1b: scan 12544 (bin,block) counts in LDS ----------------
__global__ __launch_bounds__(1024) void k_cscan(int* __restrict__ bhist,
                                                int* __restrict__ bbase,
                                                int* __restrict__ off) {
    __shared__ int s[SCANTOT];
    __shared__ int tsum[1024];
    int t = threadIdx.x;
    for (int i = t; i < SCANTOT; i += 1024) s[i] = bhist[i];   // coalesced
    __syncthreads();
    const int IT = (SCANTOT + 1023) / 1024;  // 13
    int base_i = t * IT;
    int sum = 0;
    for (int j = 0; j < IT; ++j) {
        int i = base_i + j;
        if (i < SCANTOT) sum += s[i];
    }
    tsum[t] = sum;
    __syncthreads();
    for (int d = 1; d < 1024; d <<= 1) {
        int v = (t >= d) ? tsum[t - d] : 0;
        __syncthreads();
        if (t >= d) tsum[t] += v;
        __syncthreads();
    }
    int run = (t > 0) ? tsum[t - 1] : 0;
    for (int j = 0; j < IT; ++j) {
        int i = base_i + j;
        if (i < SCANTOT) { int c = s[i]; s[i] = run; run += c; }
    }
    __syncthreads();
    for (int i = t; i < SCANTOT; i += 1024) bhist[i] = s[i];
    for (int i = t; i < NBUCK; i += 1024) bbase[i] = s[i * PBLK];
    if (t == 0) { bbase[NBUCK] = N_EDGES; off[N_NODES] = N_EDGES; }
}

// ---------------- pass 1c: partition edges into coarse buckets (packed) ----------------
__global__ __launch_bounds__(1024) void k_partition(const int* __restrict__ src,
                                                    const int* __restrict__ dst,
                                                    const int* __restrict__ bhist,
                                                    int* __restrict__ packed) {
    __shared__ int cur[NBUCK];
    int t = threadIdx.x;
    for (int i = t; i < NBUCK; i += 1024)
        cur[i] = bhist[i * PBLK + blockIdx.x];
    __syncthreads();
    int beg = blockIdx.x * PCHUNK, end = beg + PCHUNK;
    for (int e = beg + t; e < end; e += 1024) {
        int d = dst[e], sv = src[e];
        int slot = atomicAdd(&cur[d >> 8], 1);          // LDS atomic
        packed[slot] = ((d & 255) << 16) | sv;          // run-contiguous per (blk,bin)
    }
}

// ---------------- pass 2: per-bucket fine CSR + off + dinv ----------------
__global__ __launch_bounds__(1024) void k_fine(const int* __restrict__ packed,
                                               const int* __restrict__ bbase,
                                               int* __restrict__ off,
                                               float* __restrict__ dinv,
                                               int* __restrict__ csr_src) {
    __shared__ int hist[256];
    __shared__ int scan[256];
    __shared__ int cur[256];
    int t = threadIdx.x;
    int bucket = blockIdx.x;
    if (t < 256) hist[t] = 0;
    __syncthreads();
    int beg = bbase[bucket], end = bbase[bucket + 1];
    for (int i = beg + t; i < end; i += 1024)
        atomicAdd(&hist[packed[i] >> 16], 1);
    __syncthreads();
    if (t < 256) scan[t] = hist[t];
    __syncthreads();
    for (int d = 1; d < 256; d <<= 1) {
        int v = 0;
        if (t < 256 && t >= d) v = scan[t - d];
        __syncthreads();
        if (t < 256 && t >= d) scan[t] += v;
        __syncthreads();
    }
    if (t < 256) {
        int excl = beg + scan[t] - hist[t];
        cur[t] = excl;
        int node = bucket * 256 + t;
        if (node < N_NODES) {
            off[node] = excl;
            dinv[node] = rsqrtf((float)(hist[t] + 1));   // +1 self-loop
        }
    }
    __syncthreads();
    for (int i = beg + t; i < end; i += 1024) {
        int p = packed[i];
        int slot = atomicAdd(&cur[p >> 16], 1);          // LDS atomic
        csr_src[slot] = p & 0xFFFF;                      // within one ~16KB window
    }
}

// ---------------- xl' = (x @ W1) * dinv[row], W1 in LDS ----------------
__global__ __launch_bounds__(256) void k_xw64(const float* __restrict__ x,
                                              const float* __restrict__ W,
                                              const float* __restrict__ dinv,
                                              float* __restrict__ out) {
    __shared__ float sW[IN_DIM * HID_DIM];
    int tid = threadIdx.x;
    for (int i = tid; i < IN_DIM * HID_DIM; i += 256) sW[i] = W[i];
    __syncthreads();
    int col = tid & 63;
    int row = blockIdx.x * 4 + (tid >> 6);
    if (row >= N_NODES) return;
    const float* xr = x + (size_t)row * IN_DIM;
    float acc = 0.0f;
#pragma unroll
    for (int k = 0; k < IN_DIM; ++k) acc += xr[k] * sW[k * HID_DIM + col];
    out[(size_t)row * HID_DIM + col] = acc * dinv[row];
}

// ---------------- layer-1 gather (float4): h = relu(dinv*(self+sum)+b1) ----------------
// 16 lanes per node (float4 each), 4 nodes per wave, 16 nodes per block.
__global__ __launch_bounds__(256) void k_gather64(const float* __restrict__ xlp,
                                                  const int* __restrict__ csr_src,
                                                  const int* __restrict__ off,
                                                  const float* __restrict__ dinv,
                                                  const float* __restrict__ b1,
                                                  float* __restrict__ h) {
    const float4* xlp4 = (const float4*)xlp;
    int node = blockIdx.x * 16 + (threadIdx.x >> 4);   // 50000 = 16*3125 exact
    int d4 = threadIdx.x & 15;
    int beg = off[node], end = off[node + 1];
    float4 acc = xlp4[(size_t)node * 16 + d4];         // self-loop (dinv folded in)
    int j = beg;
    for (; j + 4 <= end; j += 4) {                     // 4 nodes/wave x 4 deep = 16 gathers in flight
        int s0 = csr_src[j],     s1 = csr_src[j + 1];
        int s2 = csr_src[j + 2], s3 = csr_src[j + 3];
        float4 v0 = xlp4[(size_t)s0 * 16 + d4];
        float4 v1 = xlp4[(size_t)s1 * 16 + d4];
        float4 v2 = xlp4[(size_t)s2 * 16 + d4];
        float4 v3 = xlp4[(size_t)s3 * 16 + d4];
        acc.x += (v0.x + v1.x) + (v2.x + v3.x);
        acc.y += (v0.y + v1.y) + (v2.y + v3.y);
        acc.z += (v0.z + v1.z) + (v2.z + v3.z);
        acc.w += (v0.w + v1.w) + (v2.w + v3.w);
    }
    for (; j < end; ++j) {
        float4 v = xlp4[(size_t)csr_src[j] * 16 + d4];
        acc.x += v.x; acc.y += v.y; acc.z += v.z; acc.w += v.w;
    }
    float dv = dinv[node];
    float4 bb = ((const float4*)b1)[d4];
    float4 r;
    r.x = fmaxf(dv * acc.x + bb.x, 0.0f);
    r.y = fmaxf(dv * acc.y + bb.y, 0.0f);
    r.z = fmaxf(dv * acc.z + bb.z, 0.0f);
    r.w = fmaxf(dv * acc.w + bb.w, 0.0f);
    ((float4*)h)[(size_t)node * 16 + d4] = r;
}

// ---------------- hl' = (h @ W2) * dinv[row], W2 in LDS ----------------
__global__ __launch_bounds__(256) void k_xw10(const float* __restrict__ h,
                                              const float* __restrict__ W,
                                              const float* __restrict__ dinv,
                                              float* __restrict__ out) {
    __shared__ float sW[HID_DIM * N_CLS];
    int tid = threadIdx.x;
    for (int i = tid; i < HID_DIM * N_CLS; i += 256) sW[i] = W[i];
    __syncthreads();
    int idx = blockIdx.x * 256 + tid;
    if (idx >= N_NODES * N_CLS) return;
    int row = idx / N_CLS;
    int col = idx - row * N_CLS;
    const float* hr = h + (size_t)row * HID_DIM;
    float acc = 0.0f;
#pragma unroll
    for (int k = 0; k < HID_DIM; ++k) acc += hr[k] * sW[k * N_CLS + col];
    out[idx] = acc * dinv[row];
}

// ---------------- layer-2 gather + b2 + log_softmax, 16-lane group per node ----------------
__global__ __launch_bounds__(256) void k_gather10(const float* __restrict__ hlp,
                                                  const int* __restrict__ csr_src,
                                                  const int* __restrict__ off,
                                                  const float* __restrict__ dinv,
                                                  const float* __restrict__ b2,
                                                  float* __restrict__ out) {
    int t = threadIdx.x;
    int node = blockIdx.x * 16 + (t >> 4);
    int d = t & 15;
    if (node >= N_NODES) return;
    bool act = d < N_CLS;
    int dd = act ? d : 0;
    int beg = off[node], end = off[node + 1];
    float acc = act ? hlp[(size_t)node * N_CLS + d] : 0.0f;
    int j = beg;
    for (; j + 4 <= end; j += 4) {                     // break serial latency chain
        int s0 = csr_src[j],     s1 = csr_src[j + 1];
        int s2 = csr_src[j + 2], s3 = csr_src[j + 3];
        float v0 = hlp[(size_t)s0 * N_CLS + dd];
        float v1 = hlp[(size_t)s1 * N_CLS + dd];
        float v2 = hlp[(size_t)s2 * N_CLS + dd];
        float v3 = hlp[(size_t)s3 * N_CLS + dd];
        if (act) acc += (v0 + v1) + (v2 + v3);
    }
    for (; j < end; ++j) {
        float v = hlp[(size_t)csr_src[j] * N_CLS + dd];
        if (act) acc += v;
    }
    float v = act ? dinv[node] * acc + b2[d] : -INFINITY;
    float m = v;
#pragma unroll
    for (int k = 1; k < 16; k <<= 1) m = fmaxf(m, __shfl_xor(m, k, 64));
    float ex = act ? expf(v - m) : 0.0f;
    float ssum = ex;
#pragma unroll
    for (int k = 1; k < 16; k <<= 1) ssum += __shfl_xor(ssum, k, 64);
    if (act) out[(size_t)node * N_CLS + d] = v - m - logf(ssum);
}

extern "C" void kernel_launch(void* const* d_in, const int* in_sizes, int n_in,
                              void* d_out, int out_size, void* d_ws, size_t ws_size,
                              hipStream_t stream) {
    const float* x  = (const float*)d_in[0];
    const int*   ei = (const int*)d_in[1];
    const float* W1 = (const float*)d_in[2];
    const float* b1 = (const float*)d_in[3];
    const float* W2 = (const float*)d_in[4];
    const float* b2 = (const float*)d_in[5];
    float* out = (float*)d_out;

    const int* src = ei;             // edge_index[0]
    const int* dst = ei + N_EDGES;   // edge_index[1]

    // workspace layout (all segment sizes multiples of 16B)
    int*   bhist   = (int*)d_ws;                  // 12544 (pad 12800)
    int*   bbase   = bhist + 12800;               // 197  (pad 256)
    int*   off     = bbase + 256;                 // 50001 (pad 50432)
    int*   packed  = off + 50432;                 // 800000
    int*   csr_src = packed + N_EDGES;            // 800000
    float* dinv    = (float*)(csr_src + N_EDGES); // 50000 (pad 50048)
    float* xl      = dinv + 50048;                // 3,200,000
    float* h       = xl + (size_t)N_NODES * 64;   // 3,200,000
    float* hl      = xl;                          // aliases dead xl

    const int B = 256;
    int g_rows4 = (N_NODES + 3) / 4;              // 12500
    int g_n10   = (N_NODES * N_CLS + B - 1) / B;  // 1954
    int g_g16   = N_NODES / 16;                   // 3125 (exact)

    k_chist    <<<PBLK,  1024, 0, stream>>>(dst, bhist);
    k_cscan    <<<1,     1024, 0, stream>>>(bhist, bbase, off);
    k_partition<<<PBLK,  1024, 0, stream>>>(src, dst, bhist, packed);
    k_fine     <<<NBUCK, 1024, 0, stream>>>(packed, bbase, off, dinv, csr_src);
    k_xw64     <<<g_rows4, B, 0, stream>>>(x, W1, dinv, xl);
    k_gather64 <<<g_g16,   B, 0, stream>>>(xl, csr_src, off, dinv, b1, h);
    k_xw10     <<<g_n10,   B, 0, stream>>>(h, W2, dinv, hl);
    k_gather10 <<<g_g16,   B, 0, stream>>>(hl, csr_src, off, dinv, b2, out);
    (void)in_sizes; (void)n_in; (void)out_size; (void)ws_size;
}

// Round 7
// 170.310 us; speedup vs baseline: 1.5824x; 1.1104x over previous
//
#include <hip/hip_runtime.h>
#include <math.h>

#define N_NODES  50000
#define N_EDGES  800000
#define IN_DIM   64
#define HID_DIM  64
#define N_CLS    10
#define NBUCK    196      // ceil(N_NODES/256) coarse buckets (dst >> 8)
#define PBLK     64       // partition blocks
#define PCHUNK   (N_EDGES / PBLK)   // 12500 edges per partition block (exact)
#define SCANTOT  (NBUCK * PBLK)     // 12544

// ---------------- pass 1a: per-block coarse histogram (dst>>8) ----------------
__global__ __launch_bounds__(1024) void k_chist(const int* __restrict__ dst,
                                                int* __restrict__ bhist) {
    __shared__ int lh[NBUCK];
    int t = threadIdx.x;
    for (int i = t; i < NBUCK; i += 1024) lh[i] = 0;
    __syncthreads();
    int beg = blockIdx.x * PCHUNK, end = beg + PCHUNK;
    for (int e = beg + t; e < end; e += 1024)
        atomicAdd(&lh[dst[e] >> 8], 1);          // LDS atomic
    __syncthreads();
    for (int i = t; i < NBUCK; i += 1024)
        bhist[i * PBLK + blockIdx.x] = lh[i];    // bin-major
}

// ---------------- pass 1b: scan 12544 (bin,block) counts in LDS ----------------
__global__ __launch_bounds__(1024) void k_cscan(int* __restrict__ bhist,
                                                int* __restrict__ bbase,
                                                int* __restrict__ off) {
    __shared__ int s[SCANTOT];
    __shared__ int tsum[1024];
    int t = threadIdx.x;
    for (int i = t; i < SCANTOT; i += 1024) s[i] = bhist[i];   // coalesced
    __syncthreads();
    const int IT = (SCANTOT + 1023) / 1024;  // 13
    int base_i = t * IT;
    int sum = 0;
    for (int j = 0; j < IT; ++j) {
        int i = base_i + j;
        if (i < SCANTOT) sum += s[i];
    }
    tsum[t] = sum;
    __syncthreads();
    for (int d = 1; d < 1024; d <<= 1) {
        int v = (t >= d) ? tsum[t - d] : 0;
        __syncthreads();
        if (t >= d) tsum[t] += v;
        __syncthreads();
    }
    int run = (t > 0) ? tsum[t - 1] : 0;
    for (int j = 0; j < IT; ++j) {
        int i = base_i + j;
        if (i < SCANTOT) { int c = s[i]; s[i] = run; run += c; }
    }
    __syncthreads();
    for (int i = t; i < SCANTOT; i += 1024) bhist[i] = s[i];
    for (int i = t; i < NBUCK; i += 1024) bbase[i] = s[i * PBLK];
    if (t == 0) { bbase[NBUCK] = N_EDGES; off[N_NODES] = N_EDGES; }
}

// ---------------- pass 1c: partition edges into coarse buckets (packed) ----------------
__global__ __launch_bounds__(1024) void k_partition(const int* __restrict__ src,
                                                    const int* __restrict__ dst,
                                                    const int* __restrict__ bhist,
                                                    int* __restrict__ packed) {
    __shared__ int cur[NBUCK];
    int t = threadIdx.x;
    for (int i = t; i < NBUCK; i += 1024)
        cur[i] = bhist[i * PBLK + blockIdx.x];
    __syncthreads();
    int beg = blockIdx.x * PCHUNK, end = beg + PCHUNK;
    for (int e = beg + t; e < end; e += 1024) {
        int d = dst[e], sv = src[e];
        int slot = atomicAdd(&cur[d >> 8], 1);          // LDS atomic
        packed[slot] = ((d & 255) << 16) | sv;          // run-contiguous per (blk,bin)
    }
}

// ---------------- pass 2: per-bucket fine CSR + off + dinv ----------------
__global__ __launch_bounds__(1024) void k_fine(const int* __restrict__ packed,
                                               const int* __restrict__ bbase,
                                               int* __restrict__ off,
                                               float* __restrict__ dinv,
                                               int* __restrict__ csr_src) {
    __shared__ int hist[256];
    __shared__ int scan[256];
    __shared__ int cur[256];
    int t = threadIdx.x;
    int bucket = blockIdx.x;
    if (t < 256) hist[t] = 0;
    __syncthreads();
    int beg = bbase[bucket], end = bbase[bucket + 1];
    for (int i = beg + t; i < end; i += 1024)
        atomicAdd(&hist[packed[i] >> 16], 1);
    __syncthreads();
    if (t < 256) scan[t] = hist[t];
    __syncthreads();
    for (int d = 1; d < 256; d <<= 1) {
        int v = 0;
        if (t < 256 && t >= d) v = scan[t - d];
        __syncthreads();
        if (t < 256 && t >= d) scan[t] += v;
        __syncthreads();
    }
    if (t < 256) {
        int excl = beg + scan[t] - hist[t];
        cur[t] = excl;
        int node = bucket * 256 + t;
        if (node < N_NODES) {
            off[node] = excl;
            dinv[node] = rsqrtf((float)(hist[t] + 1));   // +1 self-loop
        }
    }
    __syncthreads();
    for (int i = beg + t; i < end; i += 1024) {
        int p = packed[i];
        int slot = atomicAdd(&cur[p >> 16], 1);          // LDS atomic
        csr_src[slot] = p & 0xFFFF;                      // within one ~16KB window
    }
}

// ---------------- xl' = (x @ W1) * dinv[row] — 16-row tile, all-LDS inner loop ----------------
// block 256 = 16 rows x 16 col-quads; grid 3125 exact.
__global__ __launch_bounds__(256) void k_xw64(const float* __restrict__ x,
                                              const float* __restrict__ W,
                                              const float* __restrict__ dinv,
                                              float* __restrict__ out) {
    __shared__ float4 sW4[IN_DIM * 16];   // W1: 64 rows x 16 col-quads (16 KB)
    __shared__ float4 sx4[16 * 16];       // x tile: 16 rows x 16 k-quads (4 KB)
    int tid = threadIdx.x;
    const float4* W4 = (const float4*)W;
#pragma unroll
    for (int i = 0; i < 4; ++i) sW4[tid + 256 * i] = W4[tid + 256 * i];
    int rowbase = blockIdx.x * 16;
    sx4[tid] = ((const float4*)(x + (size_t)rowbase * IN_DIM))[tid];  // coalesced
    __syncthreads();
    int r  = tid >> 4;     // row in tile
    int cq = tid & 15;     // col quad
    const float4* sxr = &sx4[r * 16];
    float ax = 0.0f, ay = 0.0f, az = 0.0f, aw = 0.0f;
#pragma unroll
    for (int k4 = 0; k4 < 16; ++k4) {
        float4 xv = sxr[k4];
        float4 w0 = sW4[(k4 * 4 + 0) * 16 + cq];
        float4 w1 = sW4[(k4 * 4 + 1) * 16 + cq];
        float4 w2 = sW4[(k4 * 4 + 2) * 16 + cq];
        float4 w3 = sW4[(k4 * 4 + 3) * 16 + cq];
        ax += xv.x * w0.x + xv.y * w1.x + xv.z * w2.x + xv.w * w3.x;
        ay += xv.x * w0.y + xv.y * w1.y + xv.z * w2.y + xv.w * w3.y;
        az += xv.x * w0.z + xv.y * w1.z + xv.z * w2.z + xv.w * w3.z;
        aw += xv.x * w0.w + xv.y * w1.w + xv.z * w2.w + xv.w * w3.w;
    }
    int row = rowbase + r;
    float dv = dinv[row];
    float4 res;
    res.x = ax * dv; res.y = ay * dv; res.z = az * dv; res.w = aw * dv;
    ((float4*)out)[(size_t)row * 16 + cq] = res;
}

// ---------------- layer-1 gather (float4): h = relu(dinv*(self+sum)+b1) ----------------
// 16 lanes per node (float4 each), 4 nodes per wave, 16 nodes per block.
__global__ __launch_bounds__(256) void k_gather64(const float* __restrict__ xlp,
                                                  const int* __restrict__ csr_src,
                                                  const int* __restrict__ off,
                                                  const float* __restrict__ dinv,
                                                  const float* __restrict__ b1,
                                                  float* __restrict__ h) {
    const float4* xlp4 = (const float4*)xlp;
    int node = blockIdx.x * 16 + (threadIdx.x >> 4);   // 50000 = 16*3125 exact
    int d4 = threadIdx.x & 15;
    int beg = off[node], end = off[node + 1];
    float4 acc = xlp4[(size_t)node * 16 + d4];         // self-loop (dinv folded in)
    int j = beg;
    for (; j + 4 <= end; j += 4) {                     // 4 nodes/wave x 4 deep = 16 gathers in flight
        int s0 = csr_src[j],     s1 = csr_src[j + 1];
        int s2 = csr_src[j + 2], s3 = csr_src[j + 3];
        float4 v0 = xlp4[(size_t)s0 * 16 + d4];
        float4 v1 = xlp4[(size_t)s1 * 16 + d4];
        float4 v2 = xlp4[(size_t)s2 * 16 + d4];
        float4 v3 = xlp4[(size_t)s3 * 16 + d4];
        acc.x += (v0.x + v1.x) + (v2.x + v3.x);
        acc.y += (v0.y + v1.y) + (v2.y + v3.y);
        acc.z += (v0.z + v1.z) + (v2.z + v3.z);
        acc.w += (v0.w + v1.w) + (v2.w + v3.w);
    }
    for (; j < end; ++j) {
        float4 v = xlp4[(size_t)csr_src[j] * 16 + d4];
        acc.x += v.x; acc.y += v.y; acc.z += v.z; acc.w += v.w;
    }
    float dv = dinv[node];
    float4 bb = ((const float4*)b1)[d4];
    float4 r;
    r.x = fmaxf(dv * acc.x + bb.x, 0.0f);
    r.y = fmaxf(dv * acc.y + bb.y, 0.0f);
    r.z = fmaxf(dv * acc.z + bb.z, 0.0f);
    r.w = fmaxf(dv * acc.w + bb.w, 0.0f);
    ((float4*)h)[(size_t)node * 16 + d4] = r;
}

// ---------------- hl' = (h @ W2) * dinv[row] — 25-row tile, all-LDS inner loop ----------------
// block 256; grid 2000 exact (25 rows/block, 250 output threads).
__global__ __launch_bounds__(256) void k_xw10(const float* __restrict__ h,
                                              const float* __restrict__ W,
                                              const float* __restrict__ dinv,
                                              float* __restrict__ out) {
    __shared__ float sW[HID_DIM * N_CLS];   // 2.5 KB
    __shared__ float4 sh4[25 * 16];         // 25 rows x 16 quads (6.25 KB)
    int tid = threadIdx.x;
    for (int i = tid; i < HID_DIM * N_CLS; i += 256) sW[i] = W[i];
    int rowbase = blockIdx.x * 25;
    const float4* hb = (const float4*)(h + (size_t)rowbase * HID_DIM);
    for (int i = tid; i < 25 * 16; i += 256) sh4[i] = hb[i];   // coalesced
    __syncthreads();
    if (tid >= 250) return;
    int r = tid / N_CLS;
    int col = tid - r * N_CLS;
    const float* hr = (const float*)&sh4[r * 16];
    float acc = 0.0f;
#pragma unroll
    for (int k = 0; k < HID_DIM; ++k) acc += hr[k] * sW[k * N_CLS + col];
    int row = rowbase + r;
    out[(size_t)row * N_CLS + col] = acc * dinv[row];
}

// ---------------- layer-2 gather + b2 + log_softmax, 16-lane group per node ----------------
__global__ __launch_bounds__(256) void k_gather10(const float* __restrict__ hlp,
                                                  const int* __restrict__ csr_src,
                                                  const int* __restrict__ off,
                                                  const float* __restrict__ dinv,
                                                  const float* __restrict__ b2,
                                                  float* __restrict__ out) {
    int t = threadIdx.x;
    int node = blockIdx.x * 16 + (t >> 4);
    int d = t & 15;
    if (node >= N_NODES) return;
    bool act = d < N_CLS;
    int dd = act ? d : 0;
    int beg = off[node], end = off[node + 1];
    float acc = act ? hlp[(size_t)node * N_CLS + d] : 0.0f;
    int j = beg;
    for (; j + 4 <= end; j += 4) {                     // break serial latency chain
        int s0 = csr_src[j],     s1 = csr_src[j + 1];
        int s2 = csr_src[j + 2], s3 = csr_src[j + 3];
        float v0 = hlp[(size_t)s0 * N_CLS + dd];
        float v1 = hlp[(size_t)s1 * N_CLS + dd];
        float v2 = hlp[(size_t)s2 * N_CLS + dd];
        float v3 = hlp[(size_t)s3 * N_CLS + dd];
        if (act) acc += (v0 + v1) + (v2 + v3);
    }
    for (; j < end; ++j) {
        float v = hlp[(size_t)csr_src[j] * N_CLS + dd];
        if (act) acc += v;
    }
    float v = act ? dinv[node] * acc + b2[d] : -INFINITY;
    float m = v;
#pragma unroll
    for (int k = 1; k < 16; k <<= 1) m = fmaxf(m, __shfl_xor(m, k, 64));
    float ex = act ? expf(v - m) : 0.0f;
    float ssum = ex;
#pragma unroll
    for (int k = 1; k < 16; k <<= 1) ssum += __shfl_xor(ssum, k, 64);
    if (act) out[(size_t)node * N_CLS + d] = v - m - logf(ssum);
}

extern "C" void kernel_launch(void* const* d_in, const int* in_sizes, int n_in,
                              void* d_out, int out_size, void* d_ws, size_t ws_size,
                              hipStream_t stream) {
    const float* x  = (const float*)d_in[0];
    const int*   ei = (const int*)d_in[1];
    const float* W1 = (const float*)d_in[2];
    const float* b1 = (const float*)d_in[3];
    const float* W2 = (const float*)d_in[4];
    const float* b2 = (const float*)d_in[5];
    float* out = (float*)d_out;

    const int* src = ei;             // edge_index[0]
    const int* dst = ei + N_EDGES;   // edge_index[1]

    // workspace layout (all segment sizes multiples of 16B)
    int*   bhist   = (int*)d_ws;                  // 12544 (pad 12800)
    int*   bbase   = bhist + 12800;               // 197  (pad 256)
    int*   off     = bbase + 256;                 // 50001 (pad 50432)
    int*   packed  = off + 50432;                 // 800000
    int*   csr_src = packed + N_EDGES;            // 800000
    float* dinv    = (float*)(csr_src + N_EDGES); // 50000 (pad 50048)
    float* xl      = dinv + 50048;                // 3,200,000
    float* h       = xl + (size_t)N_NODES * 64;   // 3,200,000
    float* hl      = xl;                          // aliases dead xl

    const int B = 256;
    int g_x64  = N_NODES / 16;                    // 3125 exact
    int g_x10  = N_NODES / 25;                    // 2000 exact
    int g_g16  = N_NODES / 16;                    // 3125 exact

    k_chist    <<<PBLK,  1024, 0, stream>>>(dst, bhist);
    k_cscan    <<<1,     1024, 0, stream>>>(bhist, bbase, off);
    k_partition<<<PBLK,  1024, 0, stream>>>(src, dst, bhist, packed);
    k_fine     <<<NBUCK, 1024, 0, stream>>>(packed, bbase, off, dinv, csr_src);
    k_xw64     <<<g_x64,   B, 0, stream>>>(x, W1, dinv, xl);
    k_gather64 <<<g_g16,   B, 0, stream>>>(xl, csr_src, off, dinv, b1, h);
    k_xw10     <<<g_x10,   B, 0, stream>>>(h, W2, dinv, hl);
    k_gather10 <<<g_g16,   B, 0, stream>>>(hl, csr_src, off, dinv, b2, out);
    (void)in_sizes; (void)n_in; (void)out_size; (void)ws_size;
}